// Round 7
// baseline (236.677 us; speedup 1.0000x reference)
//
#include <hip/hip_runtime.h>

// Bahdanau attention, MI355X. B=32, S=4096, D=U=512, fp32 in/out.
// R7 = R5 shape + flattened 32-iter MFMA loop with B ring-3 / A ring-2
//     register prefetch (covers ~400+ cyc of L3 latency on W1f B-frags,
//     which L2 can't hold against the values stream), setprio dropped.
// R5: U-split acc (32 regs), fragment-linear LDS (0 conflicts), no spills.
#define NB 32
#define NS 4096
#define ND 512
#define NU 512

typedef __attribute__((ext_vector_type(8))) __bf16 bf16x8;
typedef __attribute__((ext_vector_type(8))) short short8;
typedef __attribute__((ext_vector_type(4))) float f32x4;

union Cvt8 { __bf16 h[8]; short8 s8; };

__device__ __forceinline__ float fast_tanh(float x) {
  float e = __expf(2.0f * x);
  return 1.0f - __fdividef(2.0f, e + 1.0f);
}

// ---- K0a: pack W1 (f32 [D][U]) -> bf16 MFMA B-fragment order ----
// W1f[ks][ct][lane][j]: k = ks*32 + (lane>>4)*8 + j, u = ct*16 + (lane&15)
__global__ void pack_w1_kernel(const float* __restrict__ W1, __bf16* __restrict__ W1f) {
  int idx = blockIdx.x * 256 + threadIdx.x;   // [16 ks][32 ct][64 lane]
  int l  = idx & 63;
  int ct = (idx >> 6) & 31;
  int ks = idx >> 11;
  int col   = ct * 16 + (l & 15);
  int kbase = ks * 32 + (l >> 4) * 8;
  Cvt8 u;
#pragma unroll
  for (int j = 0; j < 8; ++j) u.h[j] = (__bf16)W1[(size_t)(kbase + j) * NU + col];
  *reinterpret_cast<short8*>(W1f + (size_t)idx * 8) = u.s8;
}

// ---- K0b: pq[b][u] = query[b]@W2[:,u] + b2[u] + b1[u] ----
__global__ void proj_query_kernel(const float* __restrict__ query, const float* __restrict__ W2,
                                  const float* __restrict__ b2, const float* __restrict__ b1,
                                  float* __restrict__ pq) {
  int b = blockIdx.y;
  int u = blockIdx.x * 256 + threadIdx.x;
  const float* q = query + (size_t)b * ND;
  float acc = b2[u] + b1[u];
  for (int k = 0; k < ND; ++k) acc += q[k] * W2[(size_t)k * NU + u];
  pq[(size_t)b * NU + u] = acc;
}

// ---- K2: score[b][s] = sum_u tanh(values[b,s,:]@W1[:,u] + pq[b][u]) * V[u] ----
// One 64-row tile per block, 8 waves, fragment-linear LDS (see R5 comment).
// Flat it=0..31 loop: nb = it>>4, kg = it&15. B ring-3, A ring-2 prefetch.
__global__ __launch_bounds__(512, 4)
void score_kernel(const float* __restrict__ values, const __bf16* __restrict__ W1f,
                  const float* __restrict__ pq, const float* __restrict__ V,
                  float* __restrict__ scoreW) {
  __shared__ __align__(16) char ldsb[67584];  // 64KB tile + 2KB reduce buf
  float* sbuf = (float*)(ldsb + 65536);       // [8 waves][64 rows]

  int bid = blockIdx.x;                       // 2048 = 32 b * 64 tiles
  int b = bid >> 6;
  int s0 = (bid & 63) * 64;
  int tid = threadIdx.x;                      // 512
  int l = tid & 63;
  int w = tid >> 6;
  int lane_col = l & 15;
  int lane_k8  = l >> 4;

  // hoisted epilogue constants: 4 cols/thread = [nb][cf]
  float pqv[4], Vv[4];
#pragma unroll
  for (int nb = 0; nb < 2; ++nb)
#pragma unroll
    for (int cf = 0; cf < 2; ++cf) {
      int col = nb * 256 + w * 32 + cf * 16 + lane_col;
      pqv[nb * 2 + cf] = pq[(size_t)b * NU + col];
      Vv[nb * 2 + cf]  = V[col];
    }

  const float* vbase = values + ((size_t)b * NS + s0) * ND;

  // stage: 4096 16B chunks, 8 per thread. LDS linear; global decode per chunk.
#pragma unroll
  for (int i = 0; i < 8; ++i) {
    int c  = i * 512 + tid;
    int t  = c >> 10;
    int kg = (c >> 6) & 15;
    int ln = c & 63;
    int s  = t * 16 + (ln & 15);
    int c8 = kg * 4 + (ln >> 4);
    const float4* p = reinterpret_cast<const float4*>(vbase + (size_t)s * ND + c8 * 8);
    float4 f0 = p[0], f1 = p[1];
    Cvt8 u;
    u.h[0] = (__bf16)f0.x; u.h[1] = (__bf16)f0.y; u.h[2] = (__bf16)f0.z; u.h[3] = (__bf16)f0.w;
    u.h[4] = (__bf16)f1.x; u.h[5] = (__bf16)f1.y; u.h[6] = (__bf16)f1.z; u.h[7] = (__bf16)f1.w;
    *reinterpret_cast<short8*>(ldsb + (size_t)c * 16) = u.s8;
  }
  __syncthreads();

  float partial[4][4];                        // [t][r], carried across nb
#pragma unroll
  for (int t = 0; t < 4; ++t)
#pragma unroll
    for (int r = 0; r < 4; ++r) partial[t][r] = 0.f;

  // B-frag element offset for flat iteration j, col-frag cf:
  //   ((j>>4)*8192) + (j&15)*16384 + cf*512 from wp0
  const __bf16* wp0 = W1f + ((size_t)(w * 2) * 64 + l) * 8;

  f32x4 acc[4][2];
#pragma unroll
  for (int t = 0; t < 4; ++t)
#pragma unroll
    for (int cf = 0; cf < 2; ++cf) acc[t][cf] = (f32x4){0.f, 0.f, 0.f, 0.f};

  bf16x8 aa[2][4];                            // A ring-2
  bf16x8 bbb[3][2];                           // B ring-3

  // prologue: A(0), B(0), B(1), B(2)
#pragma unroll
  for (int t = 0; t < 4; ++t)
    aa[0][t] = *reinterpret_cast<const bf16x8*>(ldsb + (((t * 16 + 0) * 64 + l) << 4));
#pragma unroll
  for (int j = 0; j < 3; ++j)
#pragma unroll
    for (int cf = 0; cf < 2; ++cf)
      bbb[j][cf] = *reinterpret_cast<const bf16x8*>(
          wp0 + (size_t)((j >> 4) * 8192 + (j & 15) * 16384 + cf * 512));

#pragma unroll
  for (int it = 0; it < 32; ++it) {
    // A prefetch for it+1 (distinct ring slot, safe to issue before MFMAs)
    if (it + 1 < 32) {
      const int kg1 = (it + 1) & 15;
#pragma unroll
      for (int t = 0; t < 4; ++t)
        aa[(it + 1) & 1][t] =
            *reinterpret_cast<const bf16x8*>(ldsb + (((t * 16 + kg1) * 64 + l) << 4));
    }
    // MFMA cluster for it
#pragma unroll
    for (int cf = 0; cf < 2; ++cf)
#pragma unroll
      for (int t = 0; t < 4; ++t)
        acc[t][cf] = __builtin_amdgcn_mfma_f32_16x16x32_bf16(
            aa[it & 1][t], bbb[it % 3][cf], acc[t][cf], 0, 0, 0);
    // B prefetch for it+3 (slot (it+3)%3 == it%3, just consumed above)
    if (it + 3 < 32) {
      const int j = it + 3;
#pragma unroll
      for (int cf = 0; cf < 2; ++cf)
        bbb[j % 3][cf] = *reinterpret_cast<const bf16x8*>(
            wp0 + (size_t)((j >> 4) * 8192 + (j & 15) * 16384 + cf * 512));
    }
    // fold at end of each nb pass: tanh(proj + pq) * V
    if (it == 15 || it == 31) {
      const int nb = it >> 4;
#pragma unroll
      for (int cf = 0; cf < 2; ++cf)
#pragma unroll
        for (int t = 0; t < 4; ++t)
#pragma unroll
          for (int r = 0; r < 4; ++r)
            partial[t][r] += fast_tanh(acc[t][cf][r] + pqv[nb * 2 + cf]) * Vv[nb * 2 + cf];
      if (it == 15) {
#pragma unroll
        for (int t = 0; t < 4; ++t)
#pragma unroll
          for (int cf = 0; cf < 2; ++cf) acc[t][cf] = (f32x4){0.f, 0.f, 0.f, 0.f};
      }
    }
  }

  // reduce over the 16 lane_col lanes (cols), then across 8 waves via LDS
#pragma unroll
  for (int off = 1; off < 16; off <<= 1)
#pragma unroll
    for (int t = 0; t < 4; ++t)
#pragma unroll
      for (int r = 0; r < 4; ++r) partial[t][r] += __shfl_xor(partial[t][r], off);

  if (lane_col == 0) {
#pragma unroll
    for (int t = 0; t < 4; ++t)
#pragma unroll
      for (int r = 0; r < 4; ++r)
        sbuf[w * 64 + t * 16 + lane_k8 * 4 + r] = partial[t][r];
  }
  __syncthreads();
  if (tid < 64) {
    float sc = 0.f;
#pragma unroll
    for (int wv = 0; wv < 8; ++wv) sc += sbuf[wv * 64 + tid];
    scoreW[(size_t)b * NS + s0 + tid] = sc;   // bv omitted: softmax shift-invariant
  }
}

// ---- K3: softmax over S per batch -> attention weights (d_out tail) ----
__global__ void softmax_kernel(const float* __restrict__ scoreW, float* __restrict__ attn) {
  int b = blockIdx.x, tid = threadIdx.x;      // 256 threads
  __shared__ float sred[8];
  const float* sc = scoreW + (size_t)b * NS;
  float m = -3.0e38f;
  for (int s = tid; s < NS; s += 256) m = fmaxf(m, sc[s]);
#pragma unroll
  for (int off = 1; off < 64; off <<= 1) m = fmaxf(m, __shfl_xor(m, off));
  if ((tid & 63) == 0) sred[tid >> 6] = m;
  __syncthreads();
  m = fmaxf(fmaxf(sred[0], sred[1]), fmaxf(sred[2], sred[3]));
  float sum = 0.f;
  for (int s = tid; s < NS; s += 256) sum += __expf(sc[s] - m);
#pragma unroll
  for (int off = 1; off < 64; off <<= 1) sum += __shfl_xor(sum, off);
  if ((tid & 63) == 0) sred[4 + (tid >> 6)] = sum;
  __syncthreads();
  float inv = 1.f / (sred[4] + sred[5] + sred[6] + sred[7]);
  float* ab = attn + (size_t)b * NS;
  for (int s = tid; s < NS; s += 256) ab[s] = __expf(sc[s] - m) * inv;
}

// ---- K4: context partials over 256-row chunks ----
__global__ void context_partial_kernel(const float* __restrict__ values,
                                       const float* __restrict__ attn,
                                       float* __restrict__ ctxpart) {
  int blk = blockIdx.x;                       // 32 b * 16 chunks
  int b = blk >> 4, c = blk & 15;
  int tid = threadIdx.x;                      // 256
  int t2 = tid & 127;
  int sg = tid >> 7;
  const float* vb = values + ((size_t)b * NS + c * 256) * ND;
  const float* ab = attn + (size_t)b * NS + c * 256;
  f32x4 acc = {0.f, 0.f, 0.f, 0.f};
  for (int s = sg; s < 256; s += 2) {
    float wv = ab[s];
    f32x4 v = *reinterpret_cast<const f32x4*>(vb + (size_t)s * ND + t2 * 4);
    acc += v * wv;
  }
  __shared__ f32x4 red[128];
  if (sg == 1) red[t2] = acc;
  __syncthreads();
  if (sg == 0) {
    acc += red[t2];
    *reinterpret_cast<f32x4*>(ctxpart + (size_t)blk * ND + t2 * 4) = acc;
  }
}

// ---- K5: reduce chunk partials -> context_vector (d_out head) ----
__global__ void context_reduce_kernel(const float* __restrict__ ctxpart, float* __restrict__ ctx) {
  int b = blockIdx.x, tid = threadIdx.x;      // 128 threads * float4
  f32x4 acc = {0.f, 0.f, 0.f, 0.f};
  for (int c = 0; c < 16; ++c)
    acc += *reinterpret_cast<const f32x4*>(ctxpart + (size_t)(b * 16 + c) * ND + tid * 4);
  *reinterpret_cast<f32x4*>(ctx + (size_t)b * ND + tid * 4) = acc;
}

extern "C" void kernel_launch(void* const* d_in, const int* in_sizes, int n_in,
                              void* d_out, int out_size, void* d_ws, size_t ws_size,
                              hipStream_t stream) {
  const float* query  = (const float*)d_in[0];
  const float* values = (const float*)d_in[1];
  const float* W1     = (const float*)d_in[2];
  const float* b1     = (const float*)d_in[3];
  const float* W2     = (const float*)d_in[4];
  const float* b2     = (const float*)d_in[5];
  const float* V      = (const float*)d_in[6];
  // d_in[7] = bv: softmax-invariant, score not an output: dropped.

  float* ctx_out  = (float*)d_out;            // [32][512]
  float* attn_out = ctx_out + NB * ND;        // [32][4096]

  char* ws = (char*)d_ws;
  __bf16* W1f    = (__bf16*)ws;               // 512 KB
  float*  pq     = (float*)(ws + 524288);     // 64 KB
  float*  scoreW = (float*)(ws + 589824);     // 512 KB
  float*  ctxp   = (float*)(ws + 1114112);    // 1 MB

  hipLaunchKernelGGL(pack_w1_kernel,        dim3(128),     dim3(256), 0, stream, W1, W1f);
  hipLaunchKernelGGL(proj_query_kernel,     dim3(2, NB),   dim3(256), 0, stream, query, W2, b2, b1, pq);
  hipLaunchKernelGGL(score_kernel,          dim3(2048),    dim3(512), 0, stream, values, W1f, pq, V, scoreW);
  hipLaunchKernelGGL(softmax_kernel,        dim3(NB),      dim3(256), 0, stream, scoreW, attn_out);
  hipLaunchKernelGGL(context_partial_kernel,dim3(NB * 16), dim3(256), 0, stream, values, attn_out, ctxp);
  hipLaunchKernelGGL(context_reduce_kernel, dim3(NB),      dim3(128), 0, stream, ctxp, ctx_out);
}